// Round 14
// baseline (3028.890 us; speedup 1.0000x reference)
//
#include <hip/hip_runtime.h>
#include <hip/hip_bf16.h>

// ---------------------------------------------------------------------------
// Sparse 3-level U-Net, all-f32, f64 BN stats. Round 14: the big 27-tap convs
// are LDS-BANDWIDTH-bound (2 B/FMA at 4x4 tiles ~= 81% of dispatch time).
// gconv3: 8x8 (or 8x4) register tiles -> 1 B/FMA (1.5 for 96ch), BN coeffs in
// LDS, __launch_bounds__(TPB,2) to pin the 256-VGPR tier (no spill).
// Baseline R13: 2603 us.
// ---------------------------------------------------------------------------

// ---------- flat input conv (CIN=3) ----------------------------------------
__global__ __launch_bounds__(256) void conv_in(
    const float* __restrict__ feat, const int* __restrict__ nbr,
    const float* __restrict__ W, float* __restrict__ out, int N) {
    __shared__ float sW[27 * 3 * 32];
    const int tid = threadIdx.x;
    for (int e = tid; e < 27 * 96; e += 256) sW[e] = W[e];
    __syncthreads();
    long long r = (long long)blockIdx.x * 256 + tid;
    if (r >= N) return;
    float acc[32];
#pragma unroll
    for (int c = 0; c < 32; c++) acc[c] = 0.f;
    for (int k = 0; k < 27; k++) {
        int idx = nbr[r * 27 + k];
        if (idx >= 0) {
            float f0 = feat[(long long)idx * 3];
            float f1 = feat[(long long)idx * 3 + 1];
            float f2 = feat[(long long)idx * 3 + 2];
            const float* w = sW + k * 96;
#pragma unroll
            for (int c = 0; c < 32; c++)
                acc[c] += f0 * w[c] + f1 * w[32 + c] + f2 * w[64 + c];
        }
    }
    float4* op = reinterpret_cast<float4*>(out + r * 32);
#pragma unroll
    for (int j = 0; j < 8; j++)
        op[j] = make_float4(acc[4 * j], acc[4 * j + 1], acc[4 * j + 2], acc[4 * j + 3]);
}

// ---------- old-style gather conv (kept for d1 64->96) ---------------------
template<int CIN, int COUT, int K, int TR, int ACC, int WROW, bool FUSEBN, bool ACCUM>
__global__ void gconv(const float* __restrict__ feat, const int* __restrict__ nbr,
                      const float* __restrict__ W, int cioff,
                      const float* __restrict__ ab, float* __restrict__ out, int N) {
    constexpr int T  = COUT * TR;
    constexpr int RB = TR * ACC;
    __shared__ float sW[CIN * COUT];
    __shared__ float sF[RB * CIN];
    __shared__ int   sIdx[RB];
    __shared__ float sA[FUSEBN ? CIN : 1];
    __shared__ float sB[FUSEBN ? CIN : 1];
    const int tid = threadIdx.x;
    const int c   = tid % COUT;
    const int r0  = tid / COUT;
    const long long row0 = (long long)blockIdx.x * RB;
    if (FUSEBN && tid < CIN) { sA[tid] = ab[tid]; sB[tid] = ab[CIN + tid]; }
    float acc[ACC];
#pragma unroll
    for (int a = 0; a < ACC; a++) acc[a] = 0.f;
    for (int k = 0; k < K; k++) {
        __syncthreads();
        if (tid < RB) {
            long long r = row0 + tid;
            sIdx[tid] = (r < N) ? nbr[r * K + k] : -1;
        }
        for (int e = tid; e < CIN * COUT; e += T) {
            int ci = e / COUT, cc = e - ci * COUT;
            sW[e] = W[((long long)k * WROW + ci + cioff) * COUT + cc];
        }
        __syncthreads();
        for (int e = tid; e < RB * CIN; e += T) {
            int r = e / CIN, ci = e - r * CIN;
            long long idx = sIdx[r];
            float v = 0.f;
            if (idx >= 0) {
                v = feat[idx * CIN + ci];
                if (FUSEBN) { v = v * sA[ci] + sB[ci]; v = v > 0.f ? v : 0.f; }
            }
            sF[e] = v;
        }
        __syncthreads();
#pragma unroll 4
        for (int ci = 0; ci < CIN; ci++) {
            float w = sW[ci * COUT + c];
#pragma unroll
            for (int a = 0; a < ACC; a++)
                acc[a] += sF[(r0 + a * TR) * CIN + ci] * w;
        }
    }
#pragma unroll
    for (int a = 0; a < ACC; a++) {
        long long r = row0 + r0 + a * TR;
        if (r < N) {
            float* p = &out[r * COUT + c];
            *p = ACCUM ? (*p + acc[a]) : acc[a];
        }
    }
}

// ---------- pipelined 4x4 gather conv (kept for d0) ------------------------
template<int CIN, int COUT, int BR, int K, int TPB, int WROW, int MINW, bool ACCUM>
__global__ __launch_bounds__(TPB, MINW) void gconv2(
    const float* __restrict__ feat, const int* __restrict__ nbr,
    const float* __restrict__ W, int cioff,
    const float* __restrict__ ab, float* __restrict__ out, int N) {
    constexpr int CG  = COUT / 4;
    constexpr int RG  = BR / 4;
    static_assert(CG * RG == TPB, "tile/thread mismatch");
    constexpr int TPR = TPB / BR;
    constexpr int CPT = CIN / TPR;
    static_assert(TPR * BR == TPB && CPT * TPR == CIN && CPT % 4 == 0, "staging");
    constexpr int FCH = CPT / 4;
    constexpr int SFS = BR + 4;
    __shared__ float sW[CIN * COUT];
    __shared__ float sF[CIN * SFS];
    const int tid  = threadIdx.x;
    const int cg   = tid % CG;
    const int rg   = tid / CG;
    const int sr   = tid % BR;
    const int scio = (tid / BR) * CPT;
    const long long row0 = (long long)blockIdx.x * BR;
    const long long srow = row0 + sr;
    float ba[CPT], bb[CPT];
#pragma unroll
    for (int j = 0; j < CPT; j++) { ba[j] = ab[scio + j]; bb[j] = ab[CIN + scio + j]; }
    float acc[4][4];
#pragma unroll
    for (int i = 0; i < 4; i++)
#pragma unroll
        for (int l = 0; l < 4; l++) acc[i][l] = 0.f;
    float4 freg[FCH];
    int pidx = (srow < N) ? nbr[srow * K + 0] : -1;
    if (pidx >= 0) {
        const float* fr = feat + (long long)pidx * CIN + scio;
#pragma unroll
        for (int j = 0; j < FCH; j++)
            freg[j] = *reinterpret_cast<const float4*>(fr + 4 * j);
    }
    for (int k = 0; k < K; k++) {
        __syncthreads();
        for (int e = tid * 4; e < CIN * COUT; e += TPB * 4) {
            int ci = e / COUT, cc = e - ci * COUT;
            *reinterpret_cast<float4*>(sW + e) = *reinterpret_cast<const float4*>(
                W + ((long long)k * WROW + ci + cioff) * COUT + cc);
        }
        if (pidx >= 0) {
#pragma unroll
            for (int j = 0; j < FCH; j++) {
                float4 v = freg[j];
                float t0 = v.x * ba[4 * j]     + bb[4 * j];
                float t1 = v.y * ba[4 * j + 1] + bb[4 * j + 1];
                float t2 = v.z * ba[4 * j + 2] + bb[4 * j + 2];
                float t3 = v.w * ba[4 * j + 3] + bb[4 * j + 3];
                sF[(scio + 4 * j)     * SFS + sr] = t0 > 0.f ? t0 : 0.f;
                sF[(scio + 4 * j + 1) * SFS + sr] = t1 > 0.f ? t1 : 0.f;
                sF[(scio + 4 * j + 2) * SFS + sr] = t2 > 0.f ? t2 : 0.f;
                sF[(scio + 4 * j + 3) * SFS + sr] = t3 > 0.f ? t3 : 0.f;
            }
        } else {
#pragma unroll
            for (int j = 0; j < CPT; j++) sF[(scio + j) * SFS + sr] = 0.f;
        }
        __syncthreads();
        if (k + 1 < K) {
            pidx = (srow < N) ? nbr[srow * K + (k + 1)] : -1;
            if (pidx >= 0) {
                const float* fr = feat + (long long)pidx * CIN + scio;
#pragma unroll
                for (int j = 0; j < FCH; j++)
                    freg[j] = *reinterpret_cast<const float4*>(fr + 4 * j);
            }
        }
#pragma unroll 4
        for (int ci = 0; ci < CIN; ci += 4) {
#pragma unroll
            for (int j = 0; j < 4; j++) {
                float4 wv = *reinterpret_cast<const float4*>(sW + (ci + j) * COUT + 4 * cg);
                float4 fv = *reinterpret_cast<const float4*>(sF + (ci + j) * SFS + 4 * rg);
                const float wq[4] = {wv.x, wv.y, wv.z, wv.w};
                const float fq[4] = {fv.x, fv.y, fv.z, fv.w};
#pragma unroll
                for (int i = 0; i < 4; i++)
#pragma unroll
                    for (int l = 0; l < 4; l++)
                        acc[i][l] = fmaf(fq[i], wq[l], acc[i][l]);
            }
        }
    }
#pragma unroll
    for (int i = 0; i < 4; i++) {
        long long r = row0 + 4 * rg + i;
        if (r < N) {
            float* p = out + r * COUT + 4 * cg;
            if (ACCUM) {
                float4 o = *reinterpret_cast<float4*>(p);
                o.x += acc[i][0]; o.y += acc[i][1]; o.z += acc[i][2]; o.w += acc[i][3];
                *reinterpret_cast<float4*>(p) = o;
            } else {
                *reinterpret_cast<float4*>(p) =
                    make_float4(acc[i][0], acc[i][1], acc[i][2], acc[i][3]);
            }
        }
    }
}

// ---------- NEW: big-tile gather conv (ROWS x COLS per thread) -------------
// 1 B/FMA at 8x8. BN coeffs in LDS (sA/sB). Feature+index register prefetch.
// RPT rows staged per thread; TPR = TPB*RPT/BR threads per row.
template<int CIN, int COUT, int ROWS, int COLS, int BR, int K, int TPB,
         int WROW, int RPT, bool ACCUM>
__global__ __launch_bounds__(TPB, 2) void gconv3(
    const float* __restrict__ feat, const int* __restrict__ nbr,
    const float* __restrict__ W, int cioff,
    const float* __restrict__ ab, float* __restrict__ out, int N) {
    constexpr int CG  = COUT / COLS;
    constexpr int RG  = BR / ROWS;
    static_assert(CG * RG == TPB, "tile mismatch");
    constexpr int NRS = BR / RPT;            // staging row-groups
    constexpr int TPR = TPB / NRS;           // threads per row-group
    constexpr int CPT = CIN / TPR;           // ci per staging thread
    static_assert(NRS * TPR == TPB && TPR * CPT == CIN && CPT % 4 == 0, "staging");
    constexpr int FCH = CPT / 4;
    constexpr int SFS = BR + 4;
    __shared__ float sW[CIN * COUT];
    __shared__ float sF[CIN * SFS];
    __shared__ float sA[CIN], sB[CIN];
    const int tid  = threadIdx.x;
    const int cg   = tid % CG;
    const int rg   = tid / CG;
    const int srb  = (tid % NRS) * RPT;      // first staged row (in block)
    const int scio = (tid / NRS) * CPT;      // staged ci offset
    const long long row0 = (long long)blockIdx.x * BR;

    for (int e = tid; e < CIN; e += TPB) { sA[e] = ab[e]; sB[e] = ab[CIN + e]; }

    float acc[ROWS][COLS];
#pragma unroll
    for (int i = 0; i < ROWS; i++)
#pragma unroll
        for (int l = 0; l < COLS; l++) acc[i][l] = 0.f;

    float4 freg[RPT][FCH];
    int pidx[RPT];
#pragma unroll
    for (int rp = 0; rp < RPT; rp++) {
        long long r = row0 + srb + rp;
        pidx[rp] = (r < N) ? nbr[r * K + 0] : -1;
        if (pidx[rp] >= 0) {
            const float* fr = feat + (long long)pidx[rp] * CIN + scio;
#pragma unroll
            for (int j = 0; j < FCH; j++)
                freg[rp][j] = *reinterpret_cast<const float4*>(fr + 4 * j);
        }
    }

    for (int k = 0; k < K; k++) {
        __syncthreads();   // prior-iteration LDS reads done (covers sA init at k=0)
        // weights: global (L2-hot) -> LDS
        for (int e = tid * 4; e < CIN * COUT; e += TPB * 4) {
            int ci = e / COUT, cc = e - ci * COUT;
            *reinterpret_cast<float4*>(sW + e) = *reinterpret_cast<const float4*>(
                W + ((long long)k * WROW + ci + cioff) * COUT + cc);
        }
        // commit prefetched features (BN+relu from LDS coeffs), transposed
#pragma unroll
        for (int rp = 0; rp < RPT; rp++) {
            const int sr = srb + rp;
            if (pidx[rp] >= 0) {
#pragma unroll
                for (int j = 0; j < FCH; j++) {
                    float4 v = freg[rp][j];
                    int ci = scio + 4 * j;
                    float t0 = v.x * sA[ci]     + sB[ci];
                    float t1 = v.y * sA[ci + 1] + sB[ci + 1];
                    float t2 = v.z * sA[ci + 2] + sB[ci + 2];
                    float t3 = v.w * sA[ci + 3] + sB[ci + 3];
                    sF[(ci)     * SFS + sr] = t0 > 0.f ? t0 : 0.f;
                    sF[(ci + 1) * SFS + sr] = t1 > 0.f ? t1 : 0.f;
                    sF[(ci + 2) * SFS + sr] = t2 > 0.f ? t2 : 0.f;
                    sF[(ci + 3) * SFS + sr] = t3 > 0.f ? t3 : 0.f;
                }
            } else {
#pragma unroll
                for (int j = 0; j < CPT; j++) sF[(scio + j) * SFS + sr] = 0.f;
            }
        }
        __syncthreads();
        // prefetch k+1 (overlaps compute)
        if (k + 1 < K) {
#pragma unroll
            for (int rp = 0; rp < RPT; rp++) {
                long long r = row0 + srb + rp;
                pidx[rp] = (r < N) ? nbr[r * K + (k + 1)] : -1;
                if (pidx[rp] >= 0) {
                    const float* fr = feat + (long long)pidx[rp] * CIN + scio;
#pragma unroll
                    for (int j = 0; j < FCH; j++)
                        freg[rp][j] = *reinterpret_cast<const float4*>(fr + 4 * j);
                }
            }
        }
        // compute
#pragma unroll 2
        for (int ci = 0; ci < CIN; ci += 4) {
#pragma unroll
            for (int j = 0; j < 4; j++) {
                float fq[ROWS], wq[COLS];
#pragma unroll
                for (int b = 0; b < ROWS / 4; b++) {
                    float4 fv = *reinterpret_cast<const float4*>(
                        sF + (ci + j) * SFS + ROWS * rg + 4 * b);
                    fq[4 * b] = fv.x; fq[4 * b + 1] = fv.y;
                    fq[4 * b + 2] = fv.z; fq[4 * b + 3] = fv.w;
                }
#pragma unroll
                for (int b = 0; b < COLS / 4; b++) {
                    float4 wv = *reinterpret_cast<const float4*>(
                        sW + (ci + j) * COUT + COLS * cg + 4 * b);
                    wq[4 * b] = wv.x; wq[4 * b + 1] = wv.y;
                    wq[4 * b + 2] = wv.z; wq[4 * b + 3] = wv.w;
                }
#pragma unroll
                for (int i = 0; i < ROWS; i++)
#pragma unroll
                    for (int l = 0; l < COLS; l++)
                        acc[i][l] = fmaf(fq[i], wq[l], acc[i][l]);
            }
        }
    }
    // store ROWS x COLS tile
#pragma unroll
    for (int i = 0; i < ROWS; i++) {
        long long r = row0 + ROWS * rg + i;
        if (r < N) {
            float* p = out + r * COUT + COLS * cg;
#pragma unroll
            for (int b = 0; b < COLS / 4; b++) {
                if (ACCUM) {
                    float4 o = *reinterpret_cast<float4*>(p + 4 * b);
                    o.x += acc[i][4 * b];     o.y += acc[i][4 * b + 1];
                    o.z += acc[i][4 * b + 2]; o.w += acc[i][4 * b + 3];
                    *reinterpret_cast<float4*>(p + 4 * b) = o;
                } else {
                    *reinterpret_cast<float4*>(p + 4 * b) = make_float4(
                        acc[i][4 * b], acc[i][4 * b + 1],
                        acc[i][4 * b + 2], acc[i][4 * b + 3]);
                }
            }
        }
    }
}

// ---------- register-blocked transposed (up) conv --------------------------
template<int CIN, int COUT, int BR, int TPB>
__global__ __launch_bounds__(TPB, 4) void upconv2(
    const float* __restrict__ featc, const int* __restrict__ rb,
    const float* __restrict__ W, const float* __restrict__ ab,
    float* __restrict__ out, int N) {
    constexpr int K   = 8;
    constexpr int CG  = COUT / 4;
    constexpr int RG  = BR / 4;
    static_assert(CG * RG == TPB, "tile/thread mismatch");
    constexpr int TPR = TPB / BR;
    constexpr int CPT = CIN / TPR;
    static_assert(TPR * BR == TPB && CPT * TPR == CIN && CPT % 4 == 0, "staging");
    constexpr int SFS = BR + 4;
    __shared__ float sW[CIN * COUT];
    __shared__ float sF[CIN * SFS];
    const int tid  = threadIdx.x;
    const int cg   = tid % CG;
    const int rg   = tid / CG;
    const int sr   = tid % BR;
    const int scio = (tid / BR) * CPT;
    const long long row0 = (long long)blockIdx.x * BR;
    const long long srow = row0 + sr;
    if (srow < N) {
        const float* fr = featc + srow * CIN + scio;
#pragma unroll
        for (int j = 0; j < CPT; j += 4) {
            float4 v = *reinterpret_cast<const float4*>(fr + j);
            float t0 = v.x * ab[scio + j]     + ab[CIN + scio + j];
            float t1 = v.y * ab[scio + j + 1] + ab[CIN + scio + j + 1];
            float t2 = v.z * ab[scio + j + 2] + ab[CIN + scio + j + 2];
            float t3 = v.w * ab[scio + j + 3] + ab[CIN + scio + j + 3];
            sF[(scio + j)     * SFS + sr] = t0 > 0.f ? t0 : 0.f;
            sF[(scio + j + 1) * SFS + sr] = t1 > 0.f ? t1 : 0.f;
            sF[(scio + j + 2) * SFS + sr] = t2 > 0.f ? t2 : 0.f;
            sF[(scio + j + 3) * SFS + sr] = t3 > 0.f ? t3 : 0.f;
        }
    } else {
#pragma unroll
        for (int j = 0; j < CPT; j++) sF[(scio + j) * SFS + sr] = 0.f;
    }
    int pidx[4];
#pragma unroll
    for (int i = 0; i < 4; i++) {
        long long r = row0 + 4 * rg + i;
        pidx[i] = (r < N) ? rb[r * K + 0] : -1;
    }
    for (int k = 0; k < K; k++) {
        __syncthreads();
        for (int e = tid * 4; e < CIN * COUT; e += TPB * 4)
            *reinterpret_cast<float4*>(sW + e) =
                *reinterpret_cast<const float4*>(W + (long long)k * CIN * COUT + e);
        __syncthreads();
        int sidx[4];
#pragma unroll
        for (int i = 0; i < 4; i++) sidx[i] = pidx[i];
        if (k + 1 < K) {
#pragma unroll
            for (int i = 0; i < 4; i++) {
                long long r = row0 + 4 * rg + i;
                pidx[i] = (r < N) ? rb[r * K + (k + 1)] : -1;
            }
        }
        float acc[4][4];
#pragma unroll
        for (int i = 0; i < 4; i++)
#pragma unroll
            for (int l = 0; l < 4; l++) acc[i][l] = 0.f;
#pragma unroll 4
        for (int ci = 0; ci < CIN; ci += 4) {
#pragma unroll
            for (int j = 0; j < 4; j++) {
                float4 wv = *reinterpret_cast<const float4*>(sW + (ci + j) * COUT + 4 * cg);
                float4 fv = *reinterpret_cast<const float4*>(sF + (ci + j) * SFS + 4 * rg);
                const float wq[4] = {wv.x, wv.y, wv.z, wv.w};
                const float fq[4] = {fv.x, fv.y, fv.z, fv.w};
#pragma unroll
                for (int i = 0; i < 4; i++)
#pragma unroll
                    for (int l = 0; l < 4; l++)
                        acc[i][l] = fmaf(fq[i], wq[l], acc[i][l]);
            }
        }
#pragma unroll
        for (int i = 0; i < 4; i++) {
            if (sidx[i] >= 0) {
                *reinterpret_cast<float4*>(out + (long long)sidx[i] * COUT + 4 * cg) =
                    make_float4(acc[i][0], acc[i][1], acc[i][2], acc[i][3]);
            }
        }
    }
}

// ---------- BN stats (two-pass, deterministic, f64) ------------------------
template<int C>
__global__ void bn_stats(const float* __restrict__ x, double* __restrict__ part, int N) {
    constexpr int RPB = 256 / C;
    __shared__ double ls[256], lq[256];
    const int tid = threadIdx.x;
    double s = 0.0, q = 0.0;
    if (tid < RPB * C) {
        const int c  = tid % C;
        const int rr = tid / C;
        for (long long r = (long long)blockIdx.x * RPB + rr; r < N;
             r += (long long)gridDim.x * RPB) {
            double v = (double)x[r * C + c];
            s += v; q += v * v;
        }
    }
    ls[tid] = s; lq[tid] = q;
    __syncthreads();
    if (tid < C) {
        for (int j = 1; j < RPB; j++) { s += ls[j * C + tid]; q += lq[j * C + tid]; }
        part[blockIdx.x * 256 + tid]       = s;
        part[blockIdx.x * 256 + 128 + tid] = q;
    }
}

__global__ void bn_fin(const double* __restrict__ part, const float* __restrict__ gb,
                       int gbfull, int goff, float* __restrict__ ab,
                       int C, int P, double invN) {
    __shared__ double ss[256], sq[256];
    const int tid = threadIdx.x;
    const int c   = tid % C;
    const int g   = tid / C;
    const int G   = 256 / C;
    double s = 0.0, q = 0.0;
    if (g < G) {
        for (int p = g; p < P; p += G) {
            s += part[p * 256 + c];
            q += part[p * 256 + 128 + c];
        }
    }
    ss[tid] = s; sq[tid] = q;
    __syncthreads();
    if (tid < C) {
        for (int j = 1; j < G; j++) { s += ss[j * C + c]; q += sq[j * C + c]; }
        double mu  = s * invN;
        double var = q * invN - mu * mu;
        double a   = (double)gb[goff + c] / sqrt(var + 1e-4);
        ab[c]     = (float)a;
        ab[C + c] = (float)((double)gb[gbfull + goff + c] - mu * a);
    }
}

// ---------- final linear (bnf fused), float4 loads -------------------------
__global__ void final_k(const float* __restrict__ x, const float* __restrict__ ab,
                        const float* __restrict__ lw, const float* __restrict__ lb,
                        float* __restrict__ out, int N) {
    long long r = (long long)blockIdx.x * blockDim.x + threadIdx.x;
    if (r >= N) return;
    float a0 = lb[0], a1 = lb[1];
    const float4* xp = reinterpret_cast<const float4*>(x + r * 32);
#pragma unroll
    for (int j = 0; j < 8; j++) {
        float4 v = xp[j];
        const float vv[4] = {v.x, v.y, v.z, v.w};
#pragma unroll
        for (int t = 0; t < 4; t++) {
            int ci = 4 * j + t;
            float u = vv[t] * ab[ci] + ab[32 + ci];
            u = u > 0.f ? u : 0.f;
            a0 += u * lw[ci * 2];
            a1 += u * lw[ci * 2 + 1];
        }
    }
    out[2 * r]     = a0;
    out[2 * r + 1] = a1;
}

extern "C" void kernel_launch(void* const* d_in, const int* in_sizes, int n_in,
                              void* d_out, int out_size, void* d_ws, size_t ws_size,
                              hipStream_t stream) {
    const long long N0 = in_sizes[0] / 3;
    const long long N1 = in_sizes[26] / 8;
    const long long N2 = in_sizes[27] / 8;
    const int P = 256;

    const float* feat = (const float*)d_in[0];
    const int* nbr0 = (const int*)d_in[23];
    const int* nbr1 = (const int*)d_in[24];
    const int* nbr2 = (const int*)d_in[25];
    const int* rb0  = (const int*)d_in[26];
    const int* rb1  = (const int*)d_in[27];

    double* part = (double*)d_ws;
    float*  ab   = (float*)(part + (long long)P * 256);
    float*  base = ab + 12 * 256;
    long long szBig = N0 * 32;
    if (N1 * 64 > szBig) szBig = N1 * 64;
    if (N2 * 96 > szBig) szBig = N2 * 96;
    long long szD = (N1 * 64 > N2 * 96) ? N1 * 64 : N2 * 96;
    float* D = base;            // x2 (N2x96), y1 (N1x64)
    float* A = D + szD;         // t0, d0, d1, u1, u0
    float* B = A + szBig;       // x0 skip (N0x32)
    float* C = B + N0 * 32;     // x1 (N1x64), y0 (N0x32)

#define STATS(CH, X, NN) bn_stats<CH><<<P, 256, 0, stream>>>(X, part, (int)(NN))
#define FIN(GBI, GBFULL, GOFF, SL, CH, NN)                                           \
    bn_fin<<<1, 256, 0, stream>>>(part, (const float*)d_in[GBI], GBFULL, GOFF,       \
                                  ab + (SL) * 256, CH, P, 1.0 / (double)(NN))
#define AB(SL) (ab + (SL) * 256)
#define WF(I) ((const float*)d_in[I])

    // ---- level 0 ----
    conv_in<<<(int)((N0 + 255) / 256), 256, 0, stream>>>(
        feat, nbr0, WF(1), A, (int)N0);                                   // t0 -> A
    STATS(32, A, N0); FIN(2, 32, 0, 0, 32, N0);                           // bn1_0
    gconv3<32, 32, 8, 8, 256, 27, 128, 32, 2, false><<<(int)((N0 + 255) / 256), 128, 0, stream>>>(
        A, nbr0, WF(3), 0, AB(0), B, (int)N0);                            // x0 -> B
    STATS(32, B, N0); FIN(4, 32, 0, 1, 32, N0);                           // bnd_0
    gconv2<32, 64, 64, 8, 256, 32, 4, false><<<(int)((N1 + 63) / 64), 256, 0, stream>>>(
        B, rb0, WF(5), 0, AB(1), A, (int)N1);                             // d0 -> A

    // ---- level 1 ----
    STATS(64, A, N1); FIN(6, 64, 0, 2, 64, N1);                           // bn1_1
    gconv3<64, 64, 8, 8, 128, 27, 128, 64, 1, false><<<(int)((N1 + 127) / 128), 128, 0, stream>>>(
        A, nbr1, WF(7), 0, AB(2), C, (int)N1);                            // x1 -> C
    STATS(64, C, N1); FIN(8, 64, 0, 3, 64, N1);                           // bnd_1
    gconv<64, 96, 8, 2, 4, 64, true, false><<<(int)((N2 + 7) / 8), 192, 0, stream>>>(
        C, rb1, WF(9), 0, AB(3), A, (int)N2);                             // d1 -> A

    // ---- level 2 ----
    STATS(96, A, N2); FIN(10, 96, 0, 4, 96, N2);                          // bn1_2
    gconv3<96, 96, 8, 4, 64, 27, 192, 96, 1, false><<<(int)((N2 + 63) / 64), 192, 0, stream>>>(
        A, nbr2, WF(11), 0, AB(4), D, (int)N2);                           // x2 -> D
    STATS(96, D, N2); FIN(12, 96, 0, 5, 96, N2);                          // bnu_1

    // ---- up to level 1 (concat channel-separable) ----
    upconv2<96, 64, 64, 256><<<(int)((N2 + 63) / 64), 256, 0, stream>>>(
        D, rb1, WF(13), AB(5), A, (int)N2);                               // u1 -> A
    STATS(64, C, N1); FIN(14, 128, 0, 6, 64, N1);                         // bn2_1 [x1]
    STATS(64, A, N1); FIN(14, 128, 64, 7, 64, N1);                        // bn2_1 [u1]
    gconv3<64, 64, 8, 8, 128, 27, 128, 128, 1, false><<<(int)((N1 + 127) / 128), 128, 0, stream>>>(
        C, nbr1, WF(15), 0, AB(6), D, (int)N1);                           // y1 p1 -> D
    gconv3<64, 64, 8, 8, 128, 27, 128, 128, 1, true><<<(int)((N1 + 127) / 128), 128, 0, stream>>>(
        A, nbr1, WF(15), 64, AB(7), D, (int)N1);                          // y1 += p2
    STATS(64, D, N1); FIN(16, 64, 0, 8, 64, N1);                          // bnu_0

    // ---- up to level 0 ----
    upconv2<64, 32, 128, 256><<<(int)((N1 + 127) / 128), 256, 0, stream>>>(
        D, rb0, WF(17), AB(8), A, (int)N1);                               // u0 -> A
    STATS(32, B, N0); FIN(18, 64, 0, 9, 32, N0);                          // bn2_0 [x0]
    STATS(32, A, N0); FIN(18, 64, 32, 10, 32, N0);                        // bn2_0 [u0]
    gconv3<32, 32, 8, 8, 256, 27, 128, 64, 2, false><<<(int)((N0 + 255) / 256), 128, 0, stream>>>(
        B, nbr0, WF(19), 0, AB(9), C, (int)N0);                           // y0 p1 -> C
    gconv3<32, 32, 8, 8, 256, 27, 128, 64, 2, true><<<(int)((N0 + 255) / 256), 128, 0, stream>>>(
        A, nbr0, WF(19), 32, AB(10), C, (int)N0);                         // y0 += p2
    STATS(32, C, N0); FIN(20, 32, 0, 11, 32, N0);                         // bnf

    final_k<<<(int)((N0 + 255) / 256), 256, 0, stream>>>(
        C, AB(11), WF(21), WF(22), (float*)d_out, (int)N0);

#undef STATS
#undef FIN
#undef AB
#undef WF
}

// Round 15
// 1656.916 us; speedup vs baseline: 1.8280x; 1.8280x over previous
//
#include <hip/hip_runtime.h>
#include <hip/hip_bf16.h>

// ---------------------------------------------------------------------------
// Sparse 3-level U-Net — Round 15: MFMA rewrite. All tensors bf16, MFMA
// 16x16x32_bf16 with f32 accumulation. No LDS, no barriers: one wave owns 16
// output rows; A-fragments are direct per-lane global gathers of bf16
// activations; B-fragments read a pre-transposed bf16 weight Wt[k][cout][ci]
// (L2-hot). BN: f64 two-pass stats (deterministic) + vectorized bnact pass.
// Layouts (guide-verified): A[m=lane&15][k=quad*8+j]; D col=lane&15,
// row=quad*4+reg. Baseline R13: 2603 us (R14 regressed 3029).
// ---------------------------------------------------------------------------

typedef __hip_bfloat16 hbf;
typedef __attribute__((ext_vector_type(8))) short short8;
typedef __attribute__((ext_vector_type(4))) float f32x4;

__device__ inline float b2f(short s) {
    unsigned u = ((unsigned)(unsigned short)s) << 16;
    float f; __builtin_memcpy(&f, &u, 4); return f;
}
__device__ inline short f2b(float f) {
    hbf h = __float2bfloat16(f);
    short s; __builtin_memcpy(&s, &h, 2); return s;
}

// ---------- weight prep: f32 [K][CI][CO] -> bf16 Wt [K][CO][CI] ------------
__global__ void wprep(const float* __restrict__ w, short* __restrict__ wt,
                      int K, int CI, int CO) {
    int e = blockIdx.x * blockDim.x + threadIdx.x;
    if (e >= K * CI * CO) return;
    int k = e / (CI * CO);
    int rem = e - k * CI * CO;
    int ci = rem / CO;
    int co = rem - ci * CO;
    wt[((long long)k * CO + co) * CI + ci] = f2b(w[e]);
}

// ---------- input conv (CIN=3, f32 VALU, bf16 out) -------------------------
__global__ __launch_bounds__(256) void conv_in(
    const float* __restrict__ feat, const int* __restrict__ nbr,
    const float* __restrict__ W, short* __restrict__ out, int N) {
    __shared__ float sW[27 * 96];
    const int tid = threadIdx.x;
    for (int e = tid; e < 27 * 96; e += 256) sW[e] = W[e];
    __syncthreads();
    long long r = (long long)blockIdx.x * 256 + tid;
    if (r >= N) return;
    float acc[32];
#pragma unroll
    for (int c = 0; c < 32; c++) acc[c] = 0.f;
    for (int k = 0; k < 27; k++) {
        int idx = nbr[r * 27 + k];
        if (idx >= 0) {
            float f0 = feat[(long long)idx * 3];
            float f1 = feat[(long long)idx * 3 + 1];
            float f2 = feat[(long long)idx * 3 + 2];
            const float* w = sW + k * 96;
#pragma unroll
            for (int c = 0; c < 32; c++)
                acc[c] += f0 * w[c] + f1 * w[32 + c] + f2 * w[64 + c];
        }
    }
#pragma unroll
    for (int c = 0; c < 32; c++) out[r * 32 + c] = f2b(acc[c]);
}

// ---------- MFMA gather conv (1 or 2 sources, K taps) ----------------------
// out[r, co] = sum_k sum_ci actA[nbr[r,k], ci] * Wt[k][co][ci]  (+ actB part)
template<int CI1, int CI2, int COUT, int K>
__global__ __launch_bounds__(256) void gmfma(
    const short* __restrict__ fA, const short* __restrict__ fB,
    const int* __restrict__ nbr, const short* __restrict__ Wt,
    short* __restrict__ out, int N) {
    constexpr int CITOT = CI1 + CI2;
    constexpr int NT = COUT / 16;
    const int lane = threadIdx.x & 63;
    const int wid  = threadIdx.x >> 6;
    const int m    = lane & 15;
    const int quad = lane >> 4;
    const long long row0 = ((long long)blockIdx.x * 4 + wid) * 16;
    const long long r = row0 + m;
    const bool rv = r < N;

    f32x4 acc[NT];
#pragma unroll
    for (int t = 0; t < NT; t++) acc[t] = (f32x4)0.f;

    for (int k = 0; k < K; k++) {
        int idx = rv ? nbr[r * K + k] : -1;
#pragma unroll
        for (int kc = 0; kc < CI1 / 32; kc++) {
            short8 a = (short8)0;
            if (idx >= 0)
                a = *reinterpret_cast<const short8*>(
                    fA + (long long)idx * CI1 + kc * 32 + quad * 8);
#pragma unroll
            for (int t = 0; t < NT; t++) {
                short8 b = *reinterpret_cast<const short8*>(
                    Wt + (long long)(k * COUT + t * 16 + m) * CITOT + kc * 32 + quad * 8);
                acc[t] = __builtin_amdgcn_mfma_f32_16x16x32_bf16(a, b, acc[t], 0, 0, 0);
            }
        }
        if constexpr (CI2 > 0) {
#pragma unroll
            for (int kc = 0; kc < CI2 / 32; kc++) {
                short8 a = (short8)0;
                if (idx >= 0)
                    a = *reinterpret_cast<const short8*>(
                        fB + (long long)idx * CI2 + kc * 32 + quad * 8);
#pragma unroll
                for (int t = 0; t < NT; t++) {
                    short8 b = *reinterpret_cast<const short8*>(
                        Wt + (long long)(k * COUT + t * 16 + m) * CITOT + CI1 + kc * 32 + quad * 8);
                    acc[t] = __builtin_amdgcn_mfma_f32_16x16x32_bf16(a, b, acc[t], 0, 0, 0);
                }
            }
        }
    }
    // D: col = lane&15, row = quad*4 + reg
#pragma unroll
    for (int g = 0; g < 4; g++) {
        long long sr = row0 + quad * 4 + g;
        if (sr < N) {
#pragma unroll
            for (int t = 0; t < NT; t++)
                out[sr * COUT + t * 16 + m] = f2b(acc[t][g]);
        }
    }
}

// ---------- MFMA transposed (up) conv: permutation scatter -----------------
template<int CIN, int COUT>
__global__ __launch_bounds__(256) void upmfma(
    const short* __restrict__ f, const int* __restrict__ rb,
    const short* __restrict__ Wt, short* __restrict__ out, int N) {
    constexpr int NT = COUT / 16;
    constexpr int NK = CIN / 32;
    const int lane = threadIdx.x & 63;
    const int wid  = threadIdx.x >> 6;
    const int m    = lane & 15;
    const int quad = lane >> 4;
    const long long row0 = ((long long)blockIdx.x * 4 + wid) * 16;
    const long long r = row0 + m;
    const bool rv = r < N;

    short8 af[NK];
#pragma unroll
    for (int kc = 0; kc < NK; kc++) {
        af[kc] = (short8)0;
        if (rv)
            af[kc] = *reinterpret_cast<const short8*>(
                f + r * CIN + kc * 32 + quad * 8);
    }
    for (int k = 0; k < 8; k++) {
        f32x4 acc[NT];
#pragma unroll
        for (int t = 0; t < NT; t++) acc[t] = (f32x4)0.f;
#pragma unroll
        for (int kc = 0; kc < NK; kc++) {
#pragma unroll
            for (int t = 0; t < NT; t++) {
                short8 b = *reinterpret_cast<const short8*>(
                    Wt + (long long)(k * COUT + t * 16 + m) * CIN + kc * 32 + quad * 8);
                acc[t] = __builtin_amdgcn_mfma_f32_16x16x32_bf16(af[kc], b, acc[t], 0, 0, 0);
            }
        }
#pragma unroll
        for (int g = 0; g < 4; g++) {
            long long sr = row0 + quad * 4 + g;
            int sidx = (sr < N) ? rb[sr * 8 + k] : -1;
            if (sidx >= 0) {
#pragma unroll
                for (int t = 0; t < NT; t++)
                    out[(long long)sidx * COUT + t * 16 + m] = f2b(acc[t][g]);
            }
        }
    }
}

// ---------- BN stats over bf16 (two-pass, deterministic, f64) --------------
template<int C>
__global__ void bn_stats(const short* __restrict__ x, double* __restrict__ part, int N) {
    constexpr int RPB = 256 / C;
    __shared__ double ls[256], lq[256];
    const int tid = threadIdx.x;
    double s = 0.0, q = 0.0;
    if (tid < RPB * C) {
        const int c  = tid % C;
        const int rr = tid / C;
        for (long long r = (long long)blockIdx.x * RPB + rr; r < N;
             r += (long long)gridDim.x * RPB) {
            double v = (double)b2f(x[r * C + c]);
            s += v; q += v * v;
        }
    }
    ls[tid] = s; lq[tid] = q;
    __syncthreads();
    if (tid < C) {
        for (int j = 1; j < RPB; j++) { s += ls[j * C + tid]; q += lq[j * C + tid]; }
        part[blockIdx.x * 256 + tid]       = s;
        part[blockIdx.x * 256 + 128 + tid] = q;
    }
}

__global__ void bn_fin(const double* __restrict__ part, const float* __restrict__ gb,
                       int gbfull, int goff, float* __restrict__ ab,
                       int C, int P, double invN) {
    __shared__ double ss[256], sq[256];
    const int tid = threadIdx.x;
    const int c   = tid % C;
    const int g   = tid / C;
    const int G   = 256 / C;
    double s = 0.0, q = 0.0;
    if (g < G) {
        for (int p = g; p < P; p += G) {
            s += part[p * 256 + c];
            q += part[p * 256 + 128 + c];
        }
    }
    ss[tid] = s; sq[tid] = q;
    __syncthreads();
    if (tid < C) {
        for (int j = 1; j < G; j++) { s += ss[j * C + c]; q += sq[j * C + c]; }
        double mu  = s * invN;
        double var = q * invN - mu * mu;
        double a   = (double)gb[goff + c] / sqrt(var + 1e-4);
        ab[c]     = (float)a;
        ab[C + c] = (float)((double)gb[gbfull + goff + c] - mu * a);
    }
}

// ---------- bnact: y = relu(x*a + b), bf16 -> bf16, 8 elems/thread ---------
template<int C>
__global__ void bnact(const short* __restrict__ x, const float* __restrict__ ab,
                      short* __restrict__ y, long long total8) {
    long long i = (long long)blockIdx.x * blockDim.x + threadIdx.x;
    if (i >= total8) return;
    long long base = i * 8;
    int c0 = (int)(base % C);
    short8 v = *reinterpret_cast<const short8*>(x + base);
    short8 o;
#pragma unroll
    for (int j = 0; j < 8; j++) {
        float f = b2f(v[j]) * ab[c0 + j] + ab[C + c0 + j];
        o[j] = f2b(f > 0.f ? f : 0.f);
    }
    *reinterpret_cast<short8*>(y + base) = o;
}

// ---------- final linear (bnf fused), bf16 in, f32 out ---------------------
__global__ void final_k(const short* __restrict__ x, const float* __restrict__ ab,
                        const float* __restrict__ lw, const float* __restrict__ lb,
                        float* __restrict__ out, int N) {
    long long r = (long long)blockIdx.x * blockDim.x + threadIdx.x;
    if (r >= N) return;
    float a0 = lb[0], a1 = lb[1];
#pragma unroll
    for (int j = 0; j < 4; j++) {
        short8 v = *reinterpret_cast<const short8*>(x + r * 32 + j * 8);
#pragma unroll
        for (int t = 0; t < 8; t++) {
            int ci = 8 * j + t;
            float u = b2f(v[t]) * ab[ci] + ab[32 + ci];
            u = u > 0.f ? u : 0.f;
            a0 += u * lw[ci * 2];
            a1 += u * lw[ci * 2 + 1];
        }
    }
    out[2 * r]     = a0;
    out[2 * r + 1] = a1;
}

extern "C" void kernel_launch(void* const* d_in, const int* in_sizes, int n_in,
                              void* d_out, int out_size, void* d_ws, size_t ws_size,
                              hipStream_t stream) {
    const long long N0 = in_sizes[0] / 3;
    const long long N1 = in_sizes[26] / 8;
    const long long N2 = in_sizes[27] / 8;
    const int P = 256;

    const float* feat = (const float*)d_in[0];
    const int* nbr0 = (const int*)d_in[23];
    const int* nbr1 = (const int*)d_in[24];
    const int* nbr2 = (const int*)d_in[25];
    const int* rb0  = (const int*)d_in[26];
    const int* rb1  = (const int*)d_in[27];

    // ---- arena ----
    char* p = (char*)d_ws;
    double* part = (double*)p;            p += (size_t)P * 256 * 8;     // 512 KB
    float*  ab   = (float*)p;             p += 12 * 256 * 4;
    // transposed bf16 weights (9 layers)
    const int wLayer[9] = {3, 5, 7, 9, 11, 13, 15, 17, 19};
    const int wK[9]  = {27, 8, 27, 8, 27, 8, 27, 8, 27};
    const int wCI[9] = {32, 32, 64, 64, 96, 96, 128, 64, 64};
    const int wCO[9] = {32, 64, 64, 96, 96, 64, 64, 32, 32};
    short* wt[9];
    for (int i = 0; i < 9; i++) {
        wt[i] = (short*)p;
        size_t n = (size_t)wK[i] * wCI[i] * wCO[i];
        p += ((n * 2 + 63) & ~(size_t)63);
    }
    auto balloc = [&](long long elems) {
        short* q = (short*)p;
        p += (((size_t)elems * 2 + 63) & ~(size_t)63);
        return q;
    };
    short* R0 = balloc(N0 * 32);   // t0 / d0 / d1 / u1 / u0 (raw)
    short* R1 = balloc(N0 * 32);   // x0 raw (persist)
    short* R2 = balloc(N1 * 64);   // x1 raw (persist)
    short* R3 = balloc(N0 * 32);   // x2 / y1 / y0 (raw)
    short* Xb = balloc(N0 * 32);   // bnact out #1
    short* Yb = balloc(N0 * 32);   // bnact out #2

    // ---- weight prep ----
    for (int i = 0; i < 9; i++) {
        int n = wK[i] * wCI[i] * wCO[i];
        wprep<<<(n + 255) / 256, 256, 0, stream>>>(
            (const float*)d_in[wLayer[i]], wt[i], wK[i], wCI[i], wCO[i]);
    }

#define STATS(CH, X, NN) bn_stats<CH><<<P, 256, 0, stream>>>(X, part, (int)(NN))
#define FIN(GBI, GBFULL, GOFF, SL, CH, NN)                                           \
    bn_fin<<<1, 256, 0, stream>>>(part, (const float*)d_in[GBI], GBFULL, GOFF,       \
                                  ab + (SL) * 256, CH, P, 1.0 / (double)(NN))
#define AB(SL) (ab + (SL) * 256)
#define ACT(CH, X, SL, Y, NN)                                                        \
    bnact<CH><<<(int)(((NN) * (CH) / 8 + 255) / 256), 256, 0, stream>>>(             \
        X, AB(SL), Y, (NN) * (CH) / 8)
#define GB(N_) (int)(((N_) + 63) / 64)

    // ---- level 0 ----
    conv_in<<<(int)((N0 + 255) / 256), 256, 0, stream>>>(
        feat, nbr0, (const float*)d_in[1], R0, (int)N0);                  // t0 -> R0
    STATS(32, R0, N0); FIN(2, 32, 0, 0, 32, N0); ACT(32, R0, 0, Xb, N0);  // bn1_0
    gmfma<32, 0, 32, 27><<<GB(N0), 256, 0, stream>>>(
        Xb, nullptr, nbr0, wt[0], R1, (int)N0);                           // x0 -> R1
    STATS(32, R1, N0); FIN(4, 32, 0, 1, 32, N0); ACT(32, R1, 1, Xb, N0);  // bnd_0
    gmfma<32, 0, 64, 8><<<GB(N1), 256, 0, stream>>>(
        Xb, nullptr, rb0, wt[1], R0, (int)N1);                            // d0 -> R0

    // ---- level 1 ----
    STATS(64, R0, N1); FIN(6, 64, 0, 2, 64, N1); ACT(64, R0, 2, Xb, N1);  // bn1_1
    gmfma<64, 0, 64, 27><<<GB(N1), 256, 0, stream>>>(
        Xb, nullptr, nbr1, wt[2], R2, (int)N1);                           // x1 -> R2
    STATS(64, R2, N1); FIN(8, 64, 0, 3, 64, N1); ACT(64, R2, 3, Xb, N1);  // bnd_1
    gmfma<64, 0, 96, 8><<<GB(N2), 256, 0, stream>>>(
        Xb, nullptr, rb1, wt[3], R0, (int)N2);                            // d1 -> R0

    // ---- level 2 ----
    STATS(96, R0, N2); FIN(10, 96, 0, 4, 96, N2); ACT(96, R0, 4, Xb, N2); // bn1_2
    gmfma<96, 0, 96, 27><<<GB(N2), 256, 0, stream>>>(
        Xb, nullptr, nbr2, wt[4], R3, (int)N2);                           // x2 -> R3
    STATS(96, R3, N2); FIN(12, 96, 0, 5, 96, N2); ACT(96, R3, 5, Xb, N2); // bnu_1

    // ---- up to level 1 ----
    upmfma<96, 64><<<GB(N2), 256, 0, stream>>>(
        Xb, rb1, wt[5], R0, (int)N2);                                     // u1 -> R0
    STATS(64, R2, N1); FIN(14, 128, 0, 6, 64, N1);                        // bn2_1 [x1]
    STATS(64, R0, N1); FIN(14, 128, 64, 7, 64, N1);                       // bn2_1 [u1]
    ACT(64, R2, 6, Xb, N1); ACT(64, R0, 7, Yb, N1);
    gmfma<64, 64, 64, 27><<<GB(N1), 256, 0, stream>>>(
        Xb, Yb, nbr1, wt[6], R3, (int)N1);                                // y1 -> R3
    STATS(64, R3, N1); FIN(16, 64, 0, 8, 64, N1); ACT(64, R3, 8, Xb, N1); // bnu_0

    // ---- up to level 0 ----
    upmfma<64, 32><<<GB(N1), 256, 0, stream>>>(
        Xb, rb0, wt[7], R0, (int)N1);                                     // u0 -> R0
    STATS(32, R1, N0); FIN(18, 64, 0, 9, 32, N0);                         // bn2_0 [x0]
    STATS(32, R0, N0); FIN(18, 64, 32, 10, 32, N0);                       // bn2_0 [u0]
    ACT(32, R1, 9, Xb, N0); ACT(32, R0, 10, Yb, N0);
    gmfma<32, 32, 32, 27><<<GB(N0), 256, 0, stream>>>(
        Xb, Yb, nbr0, wt[8], R3, (int)N0);                                // y0 -> R3
    STATS(32, R3, N0); FIN(20, 32, 0, 11, 32, N0);                        // bnf

    final_k<<<(int)((N0 + 255) / 256), 256, 0, stream>>>(
        R3, AB(11), (const float*)d_in[21], (const float*)d_in[22],
        (float*)d_out, (int)N0);

#undef STATS
#undef FIN
#undef AB
#undef ACT
#undef GB
}

// Round 16
// 1452.112 us; speedup vs baseline: 2.0859x; 1.1410x over previous
//
#include <hip/hip_runtime.h>
#include <hip/hip_bf16.h>

// ---------------------------------------------------------------------------
// Sparse 3-level U-Net — Round 16: MFMA pipeline v2. The 27-tap gather convs
// were latency-bound (MfmaUtil 4.8%, VALU 4.9%, occ 50%: serialized
// idx->gather->MFMA chain). Now: ALL K indices batch-preloaded (full MLP),
// A-fragments double-buffered (prefetch k+1 during MFMA of k), bn_stats uses
// short8 coalesced loads. Baseline R15: 1657 us.
// ---------------------------------------------------------------------------

typedef __hip_bfloat16 hbf;
typedef __attribute__((ext_vector_type(8))) short short8;
typedef __attribute__((ext_vector_type(4))) float f32x4;

__device__ inline float b2f(short s) {
    unsigned u = ((unsigned)(unsigned short)s) << 16;
    float f; __builtin_memcpy(&f, &u, 4); return f;
}
__device__ inline short f2b(float f) {
    hbf h = __float2bfloat16(f);
    short s; __builtin_memcpy(&s, &h, 2); return s;
}

// ---------- weight prep: f32 [K][CI][CO] -> bf16 Wt [K][CO][CI] ------------
__global__ void wprep(const float* __restrict__ w, short* __restrict__ wt,
                      int K, int CI, int CO) {
    int e = blockIdx.x * blockDim.x + threadIdx.x;
    if (e >= K * CI * CO) return;
    int k = e / (CI * CO);
    int rem = e - k * CI * CO;
    int ci = rem / CO;
    int co = rem - ci * CO;
    wt[((long long)k * CO + co) * CI + ci] = f2b(w[e]);
}

// ---------- input conv (CIN=3, f32 VALU, bf16 out) -------------------------
__global__ __launch_bounds__(256) void conv_in(
    const float* __restrict__ feat, const int* __restrict__ nbr,
    const float* __restrict__ W, short* __restrict__ out, int N) {
    __shared__ float sW[27 * 96];
    const int tid = threadIdx.x;
    for (int e = tid; e < 27 * 96; e += 256) sW[e] = W[e];
    __syncthreads();
    long long r = (long long)blockIdx.x * 256 + tid;
    if (r >= N) return;
    float acc[32];
#pragma unroll
    for (int c = 0; c < 32; c++) acc[c] = 0.f;
    for (int k = 0; k < 27; k++) {
        int idx = nbr[r * 27 + k];
        if (idx >= 0) {
            float f0 = feat[(long long)idx * 3];
            float f1 = feat[(long long)idx * 3 + 1];
            float f2 = feat[(long long)idx * 3 + 2];
            const float* w = sW + k * 96;
#pragma unroll
            for (int c = 0; c < 32; c++)
                acc[c] += f0 * w[c] + f1 * w[32 + c] + f2 * w[64 + c];
        }
    }
#pragma unroll
    for (int c = 0; c < 32; c++) out[r * 32 + c] = f2b(acc[c]);
}

// ---------- MFMA gather conv, pipelined (1 or 2 sources, K taps) -----------
// All K indices preloaded (independent loads, deep MLP); A-fragments double-
// buffered so gather k+1 overlaps MFMAs of k. Fully unrolled (constant idx).
template<int CI1, int CI2, int COUT, int K>
__global__ __launch_bounds__(256) void gmfma(
    const short* __restrict__ fA, const short* __restrict__ fB,
    const int* __restrict__ nbr, const short* __restrict__ Wt,
    short* __restrict__ out, int N) {
    constexpr int CITOT = CI1 + CI2;
    constexpr int NT  = COUT / 16;
    constexpr int NC1 = CI1 / 32;
    constexpr int NC2 = CI2 / 32;
    constexpr int NCH = CITOT / 32;
    const int lane = threadIdx.x & 63;
    const int wid  = threadIdx.x >> 6;
    const int m    = lane & 15;
    const int quad = lane >> 4;
    const long long row0 = ((long long)blockIdx.x * 4 + wid) * 16;
    const long long r = row0 + m;
    const bool rv = r < N;

    f32x4 acc[NT];
#pragma unroll
    for (int t = 0; t < NT; t++) acc[t] = (f32x4)0.f;

    // batch-preload all K neighbor indices (independent, contiguous per row)
    int idxs[K];
#pragma unroll
    for (int k = 0; k < K; k++) idxs[k] = rv ? nbr[r * K + k] : -1;

    short8 abuf[2][NCH];
#define LOADA(kk, bb)                                                              \
    {                                                                              \
        int _i = idxs[kk];                                                         \
        _Pragma("unroll")                                                          \
        for (int c = 0; c < NC1; c++)                                              \
            abuf[bb][c] = (_i >= 0)                                                \
                ? *reinterpret_cast<const short8*>(                                \
                      fA + (long long)_i * CI1 + c * 32 + quad * 8)                \
                : (short8)0;                                                       \
        if constexpr (NC2 > 0) {                                                   \
            _Pragma("unroll")                                                      \
            for (int c = 0; c < NC2; c++)                                          \
                abuf[bb][NC1 + c] = (_i >= 0)                                      \
                    ? *reinterpret_cast<const short8*>(                            \
                          fB + (long long)_i * CI2 + c * 32 + quad * 8)            \
                    : (short8)0;                                                   \
        }                                                                          \
    }

    LOADA(0, 0)
#pragma unroll
    for (int k = 0; k < K; k++) {
        if (k + 1 < K) LOADA(k + 1, (k + 1) & 1)
#pragma unroll
        for (int c = 0; c < NCH; c++) {
#pragma unroll
            for (int t = 0; t < NT; t++) {
                short8 b = *reinterpret_cast<const short8*>(
                    Wt + (long long)(k * COUT + t * 16 + m) * CITOT + c * 32 + quad * 8);
                acc[t] = __builtin_amdgcn_mfma_f32_16x16x32_bf16(
                    abuf[k & 1][c], b, acc[t], 0, 0, 0);
            }
        }
    }
#undef LOADA
    // D: col = lane&15, row = quad*4 + reg
#pragma unroll
    for (int g = 0; g < 4; g++) {
        long long sr = row0 + quad * 4 + g;
        if (sr < N) {
#pragma unroll
            for (int t = 0; t < NT; t++)
                out[sr * COUT + t * 16 + m] = f2b(acc[t][g]);
        }
    }
}

// ---------- MFMA transposed (up) conv: permutation scatter -----------------
template<int CIN, int COUT>
__global__ __launch_bounds__(256) void upmfma(
    const short* __restrict__ f, const int* __restrict__ rb,
    const short* __restrict__ Wt, short* __restrict__ out, int N) {
    constexpr int NT = COUT / 16;
    constexpr int NK = CIN / 32;
    const int lane = threadIdx.x & 63;
    const int wid  = threadIdx.x >> 6;
    const int m    = lane & 15;
    const int quad = lane >> 4;
    const long long row0 = ((long long)blockIdx.x * 4 + wid) * 16;
    const long long r = row0 + m;
    const bool rv = r < N;

    short8 af[NK];
#pragma unroll
    for (int kc = 0; kc < NK; kc++) {
        af[kc] = (short8)0;
        if (rv)
            af[kc] = *reinterpret_cast<const short8*>(
                f + r * CIN + kc * 32 + quad * 8);
    }
    // preload scatter indices for own 4 store rows (8 octants each)
    int sidx[8][4];
#pragma unroll
    for (int g = 0; g < 4; g++) {
        long long sr = row0 + quad * 4 + g;
#pragma unroll
        for (int k = 0; k < 8; k++)
            sidx[k][g] = (sr < N) ? rb[sr * 8 + k] : -1;
    }
#pragma unroll
    for (int k = 0; k < 8; k++) {
        f32x4 acc[NT];
#pragma unroll
        for (int t = 0; t < NT; t++) acc[t] = (f32x4)0.f;
#pragma unroll
        for (int kc = 0; kc < NK; kc++) {
#pragma unroll
            for (int t = 0; t < NT; t++) {
                short8 b = *reinterpret_cast<const short8*>(
                    Wt + (long long)(k * COUT + t * 16 + m) * CIN + kc * 32 + quad * 8);
                acc[t] = __builtin_amdgcn_mfma_f32_16x16x32_bf16(af[kc], b, acc[t], 0, 0, 0);
            }
        }
#pragma unroll
        for (int g = 0; g < 4; g++) {
            if (sidx[k][g] >= 0) {
#pragma unroll
                for (int t = 0; t < NT; t++)
                    out[(long long)sidx[k][g] * COUT + t * 16 + m] = f2b(acc[t][g]);
            }
        }
    }
}

// ---------- BN stats: short8 coalesced loads, f64 deterministic ------------
template<int C>
__global__ void bn_stats(const short* __restrict__ x, double* __restrict__ part, int N) {
    constexpr int GR  = C / 8;          // short8 groups per row
    constexpr int RPB = 256 / GR;       // rows per block-pass
    constexpr int ACTIVE = GR * RPB;
    __shared__ double ls[256 * 8];
    __shared__ double lq[256 * 8];
    const int tid = threadIdx.x;
    const int g   = tid % GR;
    const int rr  = tid / GR;
    double s[8], q[8];
#pragma unroll
    for (int j = 0; j < 8; j++) { s[j] = 0.0; q[j] = 0.0; }
    if (tid < ACTIVE) {
        for (long long r = (long long)blockIdx.x * RPB + rr; r < N;
             r += (long long)gridDim.x * RPB) {
            short8 v = *reinterpret_cast<const short8*>(x + r * C + g * 8);
#pragma unroll
            for (int j = 0; j < 8; j++) {
                double f = (double)b2f(v[j]);
                s[j] += f; q[j] += f * f;
            }
        }
    }
#pragma unroll
    for (int j = 0; j < 8; j++) { ls[tid * 8 + j] = s[j]; lq[tid * 8 + j] = q[j]; }
    __syncthreads();
    if (tid < C) {
        int gg = tid / 8, jj = tid % 8;
        double S = 0.0, Q = 0.0;
        for (int r2 = 0; r2 < RPB; r2++) {
            S += ls[(r2 * GR + gg) * 8 + jj];
            Q += lq[(r2 * GR + gg) * 8 + jj];
        }
        part[blockIdx.x * 256 + tid]       = S;
        part[blockIdx.x * 256 + 128 + tid] = Q;
    }
}

__global__ void bn_fin(const double* __restrict__ part, const float* __restrict__ gb,
                       int gbfull, int goff, float* __restrict__ ab,
                       int C, int P, double invN) {
    __shared__ double ss[256], sq[256];
    const int tid = threadIdx.x;
    const int c   = tid % C;
    const int g   = tid / C;
    const int G   = 256 / C;
    double s = 0.0, q = 0.0;
    if (g < G) {
        for (int p = g; p < P; p += G) {
            s += part[p * 256 + c];
            q += part[p * 256 + 128 + c];
        }
    }
    ss[tid] = s; sq[tid] = q;
    __syncthreads();
    if (tid < C) {
        for (int j = 1; j < G; j++) { s += ss[j * C + c]; q += sq[j * C + c]; }
        double mu  = s * invN;
        double var = q * invN - mu * mu;
        double a   = (double)gb[goff + c] / sqrt(var + 1e-4);
        ab[c]     = (float)a;
        ab[C + c] = (float)((double)gb[gbfull + goff + c] - mu * a);
    }
}

// ---------- bnact: y = relu(x*a + b), bf16 -> bf16, 8 elems/thread ---------
template<int C>
__global__ void bnact(const short* __restrict__ x, const float* __restrict__ ab,
                      short* __restrict__ y, long long total8) {
    long long i = (long long)blockIdx.x * blockDim.x + threadIdx.x;
    if (i >= total8) return;
    long long base = i * 8;
    int c0 = (int)(base % C);
    short8 v = *reinterpret_cast<const short8*>(x + base);
    short8 o;
#pragma unroll
    for (int j = 0; j < 8; j++) {
        float f = b2f(v[j]) * ab[c0 + j] + ab[C + c0 + j];
        o[j] = f2b(f > 0.f ? f : 0.f);
    }
    *reinterpret_cast<short8*>(y + base) = o;
}

// ---------- final linear (bnf fused), bf16 in, f32 out ---------------------
__global__ void final_k(const short* __restrict__ x, const float* __restrict__ ab,
                        const float* __restrict__ lw, const float* __restrict__ lb,
                        float* __restrict__ out, int N) {
    long long r = (long long)blockIdx.x * blockDim.x + threadIdx.x;
    if (r >= N) return;
    float a0 = lb[0], a1 = lb[1];
#pragma unroll
    for (int j = 0; j < 4; j++) {
        short8 v = *reinterpret_cast<const short8*>(x + r * 32 + j * 8);
#pragma unroll
        for (int t = 0; t < 8; t++) {
            int ci = 8 * j + t;
            float u = b2f(v[t]) * ab[ci] + ab[32 + ci];
            u = u > 0.f ? u : 0.f;
            a0 += u * lw[ci * 2];
            a1 += u * lw[ci * 2 + 1];
        }
    }
    out[2 * r]     = a0;
    out[2 * r + 1] = a1;
}

extern "C" void kernel_launch(void* const* d_in, const int* in_sizes, int n_in,
                              void* d_out, int out_size, void* d_ws, size_t ws_size,
                              hipStream_t stream) {
    const long long N0 = in_sizes[0] / 3;
    const long long N1 = in_sizes[26] / 8;
    const long long N2 = in_sizes[27] / 8;
    const int P = 256;

    const float* feat = (const float*)d_in[0];
    const int* nbr0 = (const int*)d_in[23];
    const int* nbr1 = (const int*)d_in[24];
    const int* nbr2 = (const int*)d_in[25];
    const int* rb0  = (const int*)d_in[26];
    const int* rb1  = (const int*)d_in[27];

    // ---- arena ----
    char* p = (char*)d_ws;
    double* part = (double*)p;            p += (size_t)P * 256 * 8;     // 512 KB
    float*  ab   = (float*)p;             p += 12 * 256 * 4;
    const int wLayer[9] = {3, 5, 7, 9, 11, 13, 15, 17, 19};
    const int wK[9]  = {27, 8, 27, 8, 27, 8, 27, 8, 27};
    const int wCI[9] = {32, 32, 64, 64, 96, 96, 128, 64, 64};
    const int wCO[9] = {32, 64, 64, 96, 96, 64, 64, 32, 32};
    short* wt[9];
    for (int i = 0; i < 9; i++) {
        wt[i] = (short*)p;
        size_t n = (size_t)wK[i] * wCI[i] * wCO[i];
        p += ((n * 2 + 63) & ~(size_t)63);
    }
    auto balloc = [&](long long elems) {
        short* q = (short*)p;
        p += (((size_t)elems * 2 + 63) & ~(size_t)63);
        return q;
    };
    short* R0 = balloc(N0 * 32);   // t0 / d0 / d1 / u1 / u0 (raw)
    short* R1 = balloc(N0 * 32);   // x0 raw (persist)
    short* R2 = balloc(N1 * 64);   // x1 raw (persist)
    short* R3 = balloc(N0 * 32);   // x2 / y1 / y0 (raw)
    short* Xb = balloc(N0 * 32);   // bnact out #1
    short* Yb = balloc(N0 * 32);   // bnact out #2

    for (int i = 0; i < 9; i++) {
        int n = wK[i] * wCI[i] * wCO[i];
        wprep<<<(n + 255) / 256, 256, 0, stream>>>(
            (const float*)d_in[wLayer[i]], wt[i], wK[i], wCI[i], wCO[i]);
    }

#define STATS(CH, X, NN) bn_stats<CH><<<P, 256, 0, stream>>>(X, part, (int)(NN))
#define FIN(GBI, GBFULL, GOFF, SL, CH, NN)                                           \
    bn_fin<<<1, 256, 0, stream>>>(part, (const float*)d_in[GBI], GBFULL, GOFF,       \
                                  ab + (SL) * 256, CH, P, 1.0 / (double)(NN))
#define AB(SL) (ab + (SL) * 256)
#define ACT(CH, X, SL, Y, NN)                                                        \
    bnact<CH><<<(int)(((NN) * (CH) / 8 + 255) / 256), 256, 0, stream>>>(             \
        X, AB(SL), Y, (NN) * (CH) / 8)
#define GB(N_) (int)(((N_) + 63) / 64)

    // ---- level 0 ----
    conv_in<<<(int)((N0 + 255) / 256), 256, 0, stream>>>(
        feat, nbr0, (const float*)d_in[1], R0, (int)N0);                  // t0 -> R0
    STATS(32, R0, N0); FIN(2, 32, 0, 0, 32, N0); ACT(32, R0, 0, Xb, N0);  // bn1_0
    gmfma<32, 0, 32, 27><<<GB(N0), 256, 0, stream>>>(
        Xb, nullptr, nbr0, wt[0], R1, (int)N0);                           // x0 -> R1
    STATS(32, R1, N0); FIN(4, 32, 0, 1, 32, N0); ACT(32, R1, 1, Xb, N0);  // bnd_0
    gmfma<32, 0, 64, 8><<<GB(N1), 256, 0, stream>>>(
        Xb, nullptr, rb0, wt[1], R0, (int)N1);                            // d0 -> R0

    // ---- level 1 ----
    STATS(64, R0, N1); FIN(6, 64, 0, 2, 64, N1); ACT(64, R0, 2, Xb, N1);  // bn1_1
    gmfma<64, 0, 64, 27><<<GB(N1), 256, 0, stream>>>(
        Xb, nullptr, nbr1, wt[2], R2, (int)N1);                           // x1 -> R2
    STATS(64, R2, N1); FIN(8, 64, 0, 3, 64, N1); ACT(64, R2, 3, Xb, N1);  // bnd_1
    gmfma<64, 0, 96, 8><<<GB(N2), 256, 0, stream>>>(
        Xb, nullptr, rb1, wt[3], R0, (int)N2);                            // d1 -> R0

    // ---- level 2 ----
    STATS(96, R0, N2); FIN(10, 96, 0, 4, 96, N2); ACT(96, R0, 4, Xb, N2); // bn1_2
    gmfma<96, 0, 96, 27><<<GB(N2), 256, 0, stream>>>(
        Xb, nullptr, nbr2, wt[4], R3, (int)N2);                           // x2 -> R3
    STATS(96, R3, N2); FIN(12, 96, 0, 5, 96, N2); ACT(96, R3, 5, Xb, N2); // bnu_1

    // ---- up to level 1 ----
    upmfma<96, 64><<<GB(N2), 256, 0, stream>>>(
        Xb, rb1, wt[5], R0, (int)N2);                                     // u1 -> R0
    STATS(64, R2, N1); FIN(14, 128, 0, 6, 64, N1);                        // bn2_1 [x1]
    STATS(64, R0, N1); FIN(14, 128, 64, 7, 64, N1);                       // bn2_1 [u1]
    ACT(64, R2, 6, Xb, N1); ACT(64, R0, 7, Yb, N1);
    gmfma<64, 64, 64, 27><<<GB(N1), 256, 0, stream>>>(
        Xb, Yb, nbr1, wt[6], R3, (int)N1);                                // y1 -> R3
    STATS(64, R3, N1); FIN(16, 64, 0, 8, 64, N1); ACT(64, R3, 8, Xb, N1); // bnu_0

    // ---- up to level 0 ----
    upmfma<64, 32><<<GB(N1), 256, 0, stream>>>(
        Xb, rb0, wt[7], R0, (int)N1);                                     // u0 -> R0
    STATS(32, R1, N0); FIN(18, 64, 0, 9, 32, N0);                         // bn2_0 [x0]
    STATS(32, R0, N0); FIN(18, 64, 32, 10, 32, N0);                       // bn2_0 [u0]
    ACT(32, R1, 9, Xb, N0); ACT(32, R0, 10, Yb, N0);
    gmfma<32, 32, 32, 27><<<GB(N0), 256, 0, stream>>>(
        Xb, Yb, nbr0, wt[8], R3, (int)N0);                                // y0 -> R3
    STATS(32, R3, N0); FIN(20, 32, 0, 11, 32, N0);                        // bnf

    final_k<<<(int)((N0 + 255) / 256), 256, 0, stream>>>(
        R3, AB(11), (const float*)d_in[21], (const float*)d_in[22],
        (float*)d_out, (int)N0);

#undef STATS
#undef FIN
#undef AB
#undef ACT
#undef GB
}

// Round 17
// 963.900 us; speedup vs baseline: 3.1423x; 1.5065x over previous
//
#include <hip/hip_runtime.h>
#include <hip/hip_bf16.h>

// ---------------------------------------------------------------------------
// Sparse 3-level U-Net — Round 17: MFMA v3. B-fragment loads moved off the
// critical path: fragment-major weight tensors (wprep2) staged per-k into
// double-buffered LDS panels (coalesced copy, conflict-free ds_read_b128),
// one barrier per k. A-fragments stay register-prefetched (dist 1).
// R16 diagnosis: inline B-loads serialized ~200+cyc/k (MfmaUtil 4%).
// Baseline R16: 1452 us.
// ---------------------------------------------------------------------------

typedef __hip_bfloat16 hbf;
typedef __attribute__((ext_vector_type(8))) short short8;
typedef __attribute__((ext_vector_type(4))) float f32x4;

__device__ inline float b2f(short s) {
    unsigned u = ((unsigned)(unsigned short)s) << 16;
    float f; __builtin_memcpy(&f, &u, 4); return f;
}
__device__ inline short f2b(float f) {
    hbf h = __float2bfloat16(f);
    short s; __builtin_memcpy(&s, &h, 2); return s;
}

// ---------- weight prep: f32 [K][CI][CO] -> bf16 FRAGMENT-MAJOR ------------
// wf[(((k*NCH + c)*NT + t)*64 + lane)*8 + j] = w[k][c*32+(lane>>4)*8+j][t*16+(lane&15)]
__global__ void wprep2(const float* __restrict__ w, short* __restrict__ wf,
                       int K, int CI, int CO) {
    int total = K * CI * CO;
    int e = blockIdx.x * blockDim.x + threadIdx.x;
    if (e >= total) return;
    int NT = CO / 16, NCH = CI / 32;
    int j    = e & 7;
    int lane = (e >> 3) & 63;
    int t    = (e >> 9) % NT;
    int c    = (e / (512 * NT)) % NCH;
    int k    = e / (512 * NT * NCH);
    int ci = c * 32 + (lane >> 4) * 8 + j;
    int co = t * 16 + (lane & 15);
    wf[e] = f2b(w[((long long)k * CI + ci) * CO + co]);
}

// ---------- input conv (CIN=3, f32 VALU, bf16 out) -------------------------
__global__ __launch_bounds__(256) void conv_in(
    const float* __restrict__ feat, const int* __restrict__ nbr,
    const float* __restrict__ W, short* __restrict__ out, int N) {
    __shared__ float sW[27 * 96];
    const int tid = threadIdx.x;
    for (int e = tid; e < 27 * 96; e += 256) sW[e] = W[e];
    __syncthreads();
    long long r = (long long)blockIdx.x * 256 + tid;
    if (r >= N) return;
    float acc[32];
#pragma unroll
    for (int c = 0; c < 32; c++) acc[c] = 0.f;
    for (int k = 0; k < 27; k++) {
        int idx = nbr[r * 27 + k];
        if (idx >= 0) {
            float f0 = feat[(long long)idx * 3];
            float f1 = feat[(long long)idx * 3 + 1];
            float f2 = feat[(long long)idx * 3 + 2];
            const float* w = sW + k * 96;
#pragma unroll
            for (int c = 0; c < 32; c++)
                acc[c] += f0 * w[c] + f1 * w[32 + c] + f2 * w[64 + c];
        }
    }
#pragma unroll
    for (int c = 0; c < 32; c++) out[r * 32 + c] = f2b(acc[c]);
}

// ---------- MFMA gather conv v3: LDS-dbuf weights, reg-prefetch A ----------
template<int CI1, int CI2, int COUT, int K>
__global__ __launch_bounds__(256) void gmfma3(
    const short* __restrict__ fA, const short* __restrict__ fB,
    const int* __restrict__ nbr, const short* __restrict__ Wf,
    short* __restrict__ out, int N) {
    constexpr int CITOT = CI1 + CI2;
    constexpr int NT  = COUT / 16;
    constexpr int NC1 = CI1 / 32;
    constexpr int NC2 = CI2 / 32;
    constexpr int NCH = CITOT / 32;
    constexpr int PANEL = NCH * NT * 512;   // shorts per k-panel
    __shared__ short sB[2][PANEL];
    const int tid  = threadIdx.x;
    const int lane = tid & 63;
    const int wid  = tid >> 6;
    const int m    = lane & 15;
    const int quad = lane >> 4;
    const long long row0 = ((long long)blockIdx.x * 4 + wid) * 16;
    const long long r = row0 + m;
    const bool rv = r < N;

    f32x4 acc[NT];
#pragma unroll
    for (int t = 0; t < NT; t++) acc[t] = (f32x4)0.f;

    int idxs[K];
#pragma unroll
    for (int k = 0; k < K; k++) idxs[k] = rv ? nbr[r * K + k] : -1;

    short8 abuf[2][NCH];
#define LOADA(kk, bb)                                                              \
    {                                                                              \
        int _i = idxs[kk];                                                         \
        _Pragma("unroll")                                                          \
        for (int c = 0; c < NC1; c++)                                              \
            abuf[bb][c] = (_i >= 0)                                                \
                ? *reinterpret_cast<const short8*>(                                \
                      fA + (long long)_i * CI1 + c * 32 + quad * 8)                \
                : (short8)0;                                                       \
        if constexpr (NC2 > 0) {                                                   \
            _Pragma("unroll")                                                      \
            for (int c = 0; c < NC2; c++)                                          \
                abuf[bb][NC1 + c] = (_i >= 0)                                      \
                    ? *reinterpret_cast<const short8*>(                            \
                          fB + (long long)_i * CI2 + c * 32 + quad * 8)            \
                    : (short8)0;                                                   \
        }                                                                          \
    }
#define STAGE(kk, bb)                                                              \
    {                                                                              \
        const short* _src = Wf + (long long)(kk) * PANEL;                          \
        _Pragma("unroll")                                                          \
        for (int e = tid; e < PANEL / 8; e += 256)                                 \
            *reinterpret_cast<short8*>(&sB[bb][(size_t)e * 8]) =                   \
                *reinterpret_cast<const short8*>(_src + (size_t)e * 8);            \
    }

    LOADA(0, 0)
    STAGE(0, 0)
#pragma unroll
    for (int k = 0; k < K; k++) {
        __syncthreads();   // panel k staged; prior reads of other buffer done
        if (k + 1 < K) {
            LOADA(k + 1, (k + 1) & 1)
            STAGE(k + 1, (k + 1) & 1)
        }
#pragma unroll
        for (int c = 0; c < NCH; c++) {
#pragma unroll
            for (int t = 0; t < NT; t++) {
                short8 b = *reinterpret_cast<const short8*>(
                    &sB[k & 1][((c * NT + t) * 64 + lane) * 8]);
                acc[t] = __builtin_amdgcn_mfma_f32_16x16x32_bf16(
                    abuf[k & 1][c], b, acc[t], 0, 0, 0);
            }
        }
    }
#undef LOADA
#undef STAGE
    // D: col = lane&15, row = quad*4 + reg
#pragma unroll
    for (int g = 0; g < 4; g++) {
        long long sr = row0 + quad * 4 + g;
        if (sr < N) {
#pragma unroll
            for (int t = 0; t < NT; t++)
                out[sr * COUT + t * 16 + m] = f2b(acc[t][g]);
        }
    }
}

// ---------- MFMA transposed (up) conv v3: LDS-dbuf weights -----------------
template<int CIN, int COUT>
__global__ __launch_bounds__(256) void upmfma3(
    const short* __restrict__ f, const int* __restrict__ rb,
    const short* __restrict__ Wf, short* __restrict__ out, int N) {
    constexpr int NT = COUT / 16;
    constexpr int NK = CIN / 32;
    constexpr int PANEL = NK * NT * 512;
    __shared__ short sB[2][PANEL];
    const int tid  = threadIdx.x;
    const int lane = tid & 63;
    const int wid  = tid >> 6;
    const int m    = lane & 15;
    const int quad = lane >> 4;
    const long long row0 = ((long long)blockIdx.x * 4 + wid) * 16;
    const long long r = row0 + m;
    const bool rv = r < N;

    short8 af[NK];
#pragma unroll
    for (int kc = 0; kc < NK; kc++) {
        af[kc] = (short8)0;
        if (rv)
            af[kc] = *reinterpret_cast<const short8*>(
                f + r * CIN + kc * 32 + quad * 8);
    }
    int sidx[8][4];
#pragma unroll
    for (int g = 0; g < 4; g++) {
        long long sr = row0 + quad * 4 + g;
#pragma unroll
        for (int k = 0; k < 8; k++)
            sidx[k][g] = (sr < N) ? rb[sr * 8 + k] : -1;
    }
#define STAGE(kk, bb)                                                              \
    {                                                                              \
        const short* _src = Wf + (long long)(kk) * PANEL;                          \
        _Pragma("unroll")                                                          \
        for (int e = tid; e < PANEL / 8; e += 256)                                 \
            *reinterpret_cast<short8*>(&sB[bb][(size_t)e * 8]) =                   \
                *reinterpret_cast<const short8*>(_src + (size_t)e * 8);            \
    }
    STAGE(0, 0)
#pragma unroll
    for (int k = 0; k < 8; k++) {
        __syncthreads();
        if (k + 1 < 8) STAGE(k + 1, (k + 1) & 1)
        f32x4 acc[NT];
#pragma unroll
        for (int t = 0; t < NT; t++) acc[t] = (f32x4)0.f;
#pragma unroll
        for (int kc = 0; kc < NK; kc++) {
#pragma unroll
            for (int t = 0; t < NT; t++) {
                short8 b = *reinterpret_cast<const short8*>(
                    &sB[k & 1][((kc * NT + t) * 64 + lane) * 8]);
                acc[t] = __builtin_amdgcn_mfma_f32_16x16x32_bf16(af[kc], b, acc[t], 0, 0, 0);
            }
        }
#pragma unroll
        for (int g = 0; g < 4; g++) {
            if (sidx[k][g] >= 0) {
#pragma unroll
                for (int t = 0; t < NT; t++)
                    out[(long long)sidx[k][g] * COUT + t * 16 + m] = f2b(acc[t][g]);
            }
        }
    }
#undef STAGE
}

// ---------- BN stats: short8 coalesced loads, f64 deterministic ------------
template<int C>
__global__ void bn_stats(const short* __restrict__ x, double* __restrict__ part, int N) {
    constexpr int GR  = C / 8;
    constexpr int RPB = 256 / GR;
    constexpr int ACTIVE = GR * RPB;
    __shared__ double ls[256 * 8];
    __shared__ double lq[256 * 8];
    const int tid = threadIdx.x;
    const int g   = tid % GR;
    const int rr  = tid / GR;
    double s[8], q[8];
#pragma unroll
    for (int j = 0; j < 8; j++) { s[j] = 0.0; q[j] = 0.0; }
    if (tid < ACTIVE) {
        for (long long r = (long long)blockIdx.x * RPB + rr; r < N;
             r += (long long)gridDim.x * RPB) {
            short8 v = *reinterpret_cast<const short8*>(x + r * C + g * 8);
#pragma unroll
            for (int j = 0; j < 8; j++) {
                double f = (double)b2f(v[j]);
                s[j] += f; q[j] += f * f;
            }
        }
    }
#pragma unroll
    for (int j = 0; j < 8; j++) { ls[tid * 8 + j] = s[j]; lq[tid * 8 + j] = q[j]; }
    __syncthreads();
    if (tid < C) {
        int gg = tid / 8, jj = tid % 8;
        double S = 0.0, Q = 0.0;
        for (int r2 = 0; r2 < RPB; r2++) {
            S += ls[(r2 * GR + gg) * 8 + jj];
            Q += lq[(r2 * GR + gg) * 8 + jj];
        }
        part[blockIdx.x * 256 + tid]       = S;
        part[blockIdx.x * 256 + 128 + tid] = Q;
    }
}

__global__ void bn_fin(const double* __restrict__ part, const float* __restrict__ gb,
                       int gbfull, int goff, float* __restrict__ ab,
                       int C, int P, double invN) {
    __shared__ double ss[256], sq[256];
    const int tid = threadIdx.x;
    const int c   = tid % C;
    const int g   = tid / C;
    const int G   = 256 / C;
    double s = 0.0, q = 0.0;
    if (g < G) {
        for (int p = g; p < P; p += G) {
            s += part[p * 256 + c];
            q += part[p * 256 + 128 + c];
        }
    }
    ss[tid] = s; sq[tid] = q;
    __syncthreads();
    if (tid < C) {
        for (int j = 1; j < G; j++) { s += ss[j * C + c]; q += sq[j * C + c]; }
        double mu  = s * invN;
        double var = q * invN - mu * mu;
        double a   = (double)gb[goff + c] / sqrt(var + 1e-4);
        ab[c]     = (float)a;
        ab[C + c] = (float)((double)gb[gbfull + goff + c] - mu * a);
    }
}

// ---------- bnact: y = relu(x*a + b), bf16 -> bf16, 8 elems/thread ---------
template<int C>
__global__ void bnact(const short* __restrict__ x, const float* __restrict__ ab,
                      short* __restrict__ y, long long total8) {
    long long i = (long long)blockIdx.x * blockDim.x + threadIdx.x;
    if (i >= total8) return;
    long long base = i * 8;
    int c0 = (int)(base % C);
    short8 v = *reinterpret_cast<const short8*>(x + base);
    short8 o;
#pragma unroll
    for (int j = 0; j < 8; j++) {
        float f = b2f(v[j]) * ab[c0 + j] + ab[C + c0 + j];
        o[j] = f2b(f > 0.f ? f : 0.f);
    }
    *reinterpret_cast<short8*>(y + base) = o;
}

// ---------- final linear (bnf fused), bf16 in, f32 out ---------------------
__global__ void final_k(const short* __restrict__ x, const float* __restrict__ ab,
                        const float* __restrict__ lw, const float* __restrict__ lb,
                        float* __restrict__ out, int N) {
    long long r = (long long)blockIdx.x * blockDim.x + threadIdx.x;
    if (r >= N) return;
    float a0 = lb[0], a1 = lb[1];
#pragma unroll
    for (int j = 0; j < 4; j++) {
        short8 v = *reinterpret_cast<const short8*>(x + r * 32 + j * 8);
#pragma unroll
        for (int t = 0; t < 8; t++) {
            int ci = 8 * j + t;
            float u = b2f(v[t]) * ab[ci] + ab[32 + ci];
            u = u > 0.f ? u : 0.f;
            a0 += u * lw[ci * 2];
            a1 += u * lw[ci * 2 + 1];
        }
    }
    out[2 * r]     = a0;
    out[2 * r + 1] = a1;
}

extern "C" void kernel_launch(void* const* d_in, const int* in_sizes, int n_in,
                              void* d_out, int out_size, void* d_ws, size_t ws_size,
                              hipStream_t stream) {
    const long long N0 = in_sizes[0] / 3;
    const long long N1 = in_sizes[26] / 8;
    const long long N2 = in_sizes[27] / 8;
    const int P = 256;

    const float* feat = (const float*)d_in[0];
    const int* nbr0 = (const int*)d_in[23];
    const int* nbr1 = (const int*)d_in[24];
    const int* nbr2 = (const int*)d_in[25];
    const int* rb0  = (const int*)d_in[26];
    const int* rb1  = (const int*)d_in[27];

    // ---- arena ----
    char* p = (char*)d_ws;
    double* part = (double*)p;            p += (size_t)P * 256 * 8;     // 512 KB
    float*  ab   = (float*)p;             p += 12 * 256 * 4;
    const int wLayer[9] = {3, 5, 7, 9, 11, 13, 15, 17, 19};
    const int wK[9]  = {27, 8, 27, 8, 27, 8, 27, 8, 27};
    const int wCI[9] = {32, 32, 64, 64, 96, 96, 128, 64, 64};
    const int wCO[9] = {32, 64, 64, 96, 96, 64, 64, 32, 32};
    short* wt[9];
    for (int i = 0; i < 9; i++) {
        wt[i] = (short*)p;
        size_t n = (size_t)wK[i] * wCI[i] * wCO[i];
        p += ((n * 2 + 63) & ~(size_t)63);
    }
    auto balloc = [&](long long elems) {
        short* q = (short*)p;
        p += (((size_t)elems * 2 + 63) & ~(size_t)63);
        return q;
    };
    short* R0 = balloc(N0 * 32);   // t0 / d0 / d1 / u1 / u0 (raw)
    short* R1 = balloc(N0 * 32);   // x0 raw (persist)
    short* R2 = balloc(N1 * 64);   // x1 raw (persist)
    short* R3 = balloc(N0 * 32);   // x2 / y1 / y0 (raw)
    short* Xb = balloc(N0 * 32);   // bnact out #1
    short* Yb = balloc(N0 * 32);   // bnact out #2

    for (int i = 0; i < 9; i++) {
        int n = wK[i] * wCI[i] * wCO[i];
        wprep2<<<(n + 255) / 256, 256, 0, stream>>>(
            (const float*)d_in[wLayer[i]], wt[i], wK[i], wCI[i], wCO[i]);
    }

#define STATS(CH, X, NN) bn_stats<CH><<<P, 256, 0, stream>>>(X, part, (int)(NN))
#define FIN(GBI, GBFULL, GOFF, SL, CH, NN)                                           \
    bn_fin<<<1, 256, 0, stream>>>(part, (const float*)d_in[GBI], GBFULL, GOFF,       \
                                  ab + (SL) * 256, CH, P, 1.0 / (double)(NN))
#define AB(SL) (ab + (SL) * 256)
#define ACT(CH, X, SL, Y, NN)                                                        \
    bnact<CH><<<(int)(((NN) * (CH) / 8 + 255) / 256), 256, 0, stream>>>(             \
        X, AB(SL), Y, (NN) * (CH) / 8)
#define GB(N_) (int)(((N_) + 63) / 64)

    // ---- level 0 ----
    conv_in<<<(int)((N0 + 255) / 256), 256, 0, stream>>>(
        feat, nbr0, (const float*)d_in[1], R0, (int)N0);                  // t0 -> R0
    STATS(32, R0, N0); FIN(2, 32, 0, 0, 32, N0); ACT(32, R0, 0, Xb, N0);  // bn1_0
    gmfma3<32, 0, 32, 27><<<GB(N0), 256, 0, stream>>>(
        Xb, nullptr, nbr0, wt[0], R1, (int)N0);                           // x0 -> R1
    STATS(32, R1, N0); FIN(4, 32, 0, 1, 32, N0); ACT(32, R1, 1, Xb, N0);  // bnd_0
    gmfma3<32, 0, 64, 8><<<GB(N1), 256, 0, stream>>>(
        Xb, nullptr, rb0, wt[1], R0, (int)N1);                            // d0 -> R0

    // ---- level 1 ----
    STATS(64, R0, N1); FIN(6, 64, 0, 2, 64, N1); ACT(64, R0, 2, Xb, N1);  // bn1_1
    gmfma3<64, 0, 64, 27><<<GB(N1), 256, 0, stream>>>(
        Xb, nullptr, nbr1, wt[2], R2, (int)N1);                           // x1 -> R2
    STATS(64, R2, N1); FIN(8, 64, 0, 3, 64, N1); ACT(64, R2, 3, Xb, N1);  // bnd_1
    gmfma3<64, 0, 96, 8><<<GB(N2), 256, 0, stream>>>(
        Xb, nullptr, rb1, wt[3], R0, (int)N2);                            // d1 -> R0

    // ---- level 2 ----
    STATS(96, R0, N2); FIN(10, 96, 0, 4, 96, N2); ACT(96, R0, 4, Xb, N2); // bn1_2
    gmfma3<96, 0, 96, 27><<<GB(N2), 256, 0, stream>>>(
        Xb, nullptr, nbr2, wt[4], R3, (int)N2);                           // x2 -> R3
    STATS(96, R3, N2); FIN(12, 96, 0, 5, 96, N2); ACT(96, R3, 5, Xb, N2); // bnu_1

    // ---- up to level 1 ----
    upmfma3<96, 64><<<GB(N2), 256, 0, stream>>>(
        Xb, rb1, wt[5], R0, (int)N2);                                     // u1 -> R0
    STATS(64, R2, N1); FIN(14, 128, 0, 6, 64, N1);                        // bn2_1 [x1]
    STATS(64, R0, N1); FIN(14, 128, 64, 7, 64, N1);                       // bn2_1 [u1]
    ACT(64, R2, 6, Xb, N1); ACT(64, R0, 7, Yb, N1);
    gmfma3<64, 64, 64, 27><<<GB(N1), 256, 0, stream>>>(
        Xb, Yb, nbr1, wt[6], R3, (int)N1);                                // y1 -> R3
    STATS(64, R3, N1); FIN(16, 64, 0, 8, 64, N1); ACT(64, R3, 8, Xb, N1); // bnu_0

    // ---- up to level 0 ----
    upmfma3<64, 32><<<GB(N1), 256, 0, stream>>>(
        Xb, rb0, wt[7], R0, (int)N1);                                     // u0 -> R0
    STATS(32, R1, N0); FIN(18, 64, 0, 9, 32, N0);                         // bn2_0 [x0]
    STATS(32, R0, N0); FIN(18, 64, 32, 10, 32, N0);                       // bn2_0 [u0]
    ACT(32, R1, 9, Xb, N0); ACT(32, R0, 10, Yb, N0);
    gmfma3<32, 32, 32, 27><<<GB(N0), 256, 0, stream>>>(
        Xb, Yb, nbr0, wt[8], R3, (int)N0);                                // y0 -> R3
    STATS(32, R3, N0); FIN(20, 32, 0, 11, 32, N0);                        // bnf

    final_k<<<(int)((N0 + 255) / 256), 256, 0, stream>>>(
        R3, AB(11), (const float*)d_in[21], (const float*)d_in[22],
        (float*)d_out, (int)N0);

#undef STATS
#undef FIN
#undef AB
#undef ACT
#undef GB
}